// Round 18
// baseline (216.633 us; speedup 1.0000x reference)
//
#include <hip/hip_runtime.h>
#include <hip/hip_bf16.h>

#define SEQ 4096
#define BSZ 2
#define NH 8
#define HD 64
#define DMODEL 512

typedef __bf16 bf16_t;
typedef __bf16 bf16x8 __attribute__((ext_vector_type(8)));
typedef __bf16 bf16x4 __attribute__((ext_vector_type(4)));
typedef float f32x4 __attribute__((ext_vector_type(4)));

__device__ __forceinline__ f32x4 mfma16(bf16x8 a, bf16x8 b, f32x4 c) {
    return __builtin_amdgcn_mfma_f32_16x16x32_bf16(a, b, c, 0, 0, 0);
}

__device__ __forceinline__ bf16x8 ld8(const bf16_t* p) {
    return *reinterpret_cast<const bf16x8*>(p);
}

__device__ __forceinline__ uint32_t pack2(bf16_t a, bf16_t b) {
    union { bf16_t h[2]; uint32_t u; } x;
    x.h[0] = a; x.h[1] = b;
    return x.u;
}

// async global->LDS DMA, 16 B/lane; data lands at lds base + lane*16
__device__ __forceinline__ void gl_lds16(const bf16_t* g, bf16_t* l) {
    __builtin_amdgcn_global_load_lds(
        (const __attribute__((address_space(1))) uint32_t*)g,
        (__attribute__((address_space(3))) uint32_t*)l,
        16, 0, 0);
}

__device__ __forceinline__ bf16x4 cvt4(float4 v) {
    bf16x4 o;
    o[0] = (bf16_t)v.x; o[1] = (bf16_t)v.y; o[2] = (bf16_t)v.z; o[3] = (bf16_t)v.w;
    return o;
}

// ---------------- GEMM1: fp32 x @ fp32 W^T, all casts fused, RoPE epilogue ----------------
// A and B both staged reg-prefetch -> cvt bf16 -> ds_write at loop top; no
// DMA in this kernel (barrier = ds_write visibility only). Dbuf, 1
// barrier/iter. blockIdx.y/4 selects Wq/Wk/Wv (128-col tiles within one
// 512-col matrix).
__global__ __launch_bounds__(256) void gemm_qkv(const float* __restrict__ A,
                                                const float* __restrict__ wq,
                                                const float* __restrict__ wk,
                                                const float* __restrict__ wv,
                                                bf16_t* __restrict__ Qb,
                                                bf16_t* __restrict__ Kb,
                                                bf16_t* __restrict__ Vb,
                                                const int* __restrict__ Vpar) {
    __shared__ bf16_t As[2 * 128 * 32];   // 16 KB
    __shared__ bf16_t Bs[2 * 128 * 32];   // 16 KB
    const int lane = threadIdx.x & 63;
    const int wid = threadIdx.x >> 6;
    const int c = lane & 15, quad = lane >> 4;
    const int wm = wid & 1, wn = wid >> 1;
    const int m0 = blockIdx.x * 128;
    const int n0 = blockIdx.y * 128;

    const float* Wsrc = (blockIdx.y < 4) ? wq : (blockIdx.y < 8) ? wk : wv;
    const int nloc = n0 & 511;

    f32x4 acc[4][4];
#pragma unroll
    for (int i = 0; i < 4; i++)
#pragma unroll
        for (int j = 0; j < 4; j++) acc[i][j] = f32x4{0.f, 0.f, 0.f, 0.f};

    // staging: lane covers row wid*32 + i*8 + (lane>>3), cols (lane&7)*4..+3
    const float* Ag32 = A + (size_t)(m0 + wid * 32 + (lane >> 3)) * 512 + (lane & 7) * 4;
    const float* Bg32 = Wsrc + (size_t)(nloc + wid * 32 + (lane >> 3)) * 512 + (lane & 7) * 4;
    bf16_t* Aw = As + (wid * 32 + (lane >> 3)) * 32 + (lane & 7) * 4;
    bf16_t* Bw = Bs + (wid * 32 + (lane >> 3)) * 32 + (lane & 7) * 4;

    // pre-loop: tile 0 into regs
    float4 ar[4], br[4];
#pragma unroll
    for (int i = 0; i < 4; i++) {
        ar[i] = *reinterpret_cast<const float4*>(Ag32 + (size_t)i * 8 * 512);
        br[i] = *reinterpret_cast<const float4*>(Bg32 + (size_t)i * 8 * 512);
    }

    for (int it = 0; it < 16; it++) {
        // write tile(it) regs -> LDS buf[it&1] (cvt fp32->bf16)
        bf16_t* aw = Aw + (it & 1) * 4096;
        bf16_t* bw = Bw + (it & 1) * 4096;
#pragma unroll
        for (int i = 0; i < 4; i++) {
            *reinterpret_cast<bf16x4*>(aw + i * 8 * 32) = cvt4(ar[i]);
            *reinterpret_cast<bf16x4*>(bw + i * 8 * 32) = cvt4(br[i]);
        }

        __syncthreads();   // writes visible; prev readers done

        if (it + 1 < 16) {
            int k0 = (it + 1) * 32;
#pragma unroll
            for (int i = 0; i < 4; i++) {
                ar[i] = *reinterpret_cast<const float4*>(Ag32 + (size_t)i * 8 * 512 + k0);
                br[i] = *reinterpret_cast<const float4*>(Bg32 + (size_t)i * 8 * 512 + k0);
            }
        }

        const bf16_t* Ab = As + (it & 1) * 4096;
        const bf16_t* Bb = Bs + (it & 1) * 4096;
        bf16x8 a[4], b[4];
#pragma unroll
        for (int i = 0; i < 4; i++) a[i] = ld8(&Ab[(wm * 64 + i * 16 + c) * 32 + quad * 8]);
#pragma unroll
        for (int j = 0; j < 4; j++) b[j] = ld8(&Bb[(wn * 64 + j * 16 + c) * 32 + quad * 8]);
#pragma unroll
        for (int i = 0; i < 4; i++)
#pragma unroll
            for (int j = 0; j < 4; j++) acc[i][j] = mfma16(a[i], b[j], acc[i][j]);
    }

    const int Vv = Vpar[0];
    const float qs = 0.1803368801111204f;   // 0.125 * log2(e)
    const bool codd = (c & 1);

#pragma unroll
    for (int i = 0; i < 4; i++) {
        int mbase = m0 + wm * 64 + i * 16 + quad * 4;
#pragma unroll
        for (int j = 0; j < 4; j++) {
            int col = n0 + wn * 64 + j * 16 + c;
            int which = col >> 9;            // uniform per (wave, j)
            int h = (col >> 6) & 7;
            int d = col & 63;
            f32x4 v = acc[i][j];
            if (which < 2) {                 // rope Q / K (wave-uniform branch)
                int fidx = (d & 31) >> 1;
                float inv = exp2f((float)fidx * -0.8304820237218407f);
                bool hi = (d >= 32);
                f32x4 part;
#pragma unroll
                for (int r = 0; r < 4; r++) part[r] = __shfl_xor(v[r], 1, 64);
#pragma unroll
                for (int r = 0; r < 4; r++) {
                    int s = (mbase + r) & 4095;
                    int tq = s / Vv;
                    int vq = s - tq * Vv;
                    float ang = (float)(hi ? vq : tq) * inv;
                    float sn = __sinf(ang), cs = __cosf(ang);
                    float xe = codd ? part[r] : v[r];
                    float xo = codd ? v[r] : part[r];
                    v[r] = codd ? (xe * sn + xo * cs) : (xe * cs - xo * sn);
                }
                if (which == 0) {
#pragma unroll
                    for (int r = 0; r < 4; r++) v[r] *= qs;
                }
            }
            bf16_t* dst = (which == 0) ? Qb : ((which == 1) ? Kb : Vb);

            // paired dword stores: even lane rows 0-1, odd lane rows 2-3
            float p0 = __shfl_xor(v[0], 1, 64);
            float p1 = __shfl_xor(v[1], 1, 64);
            float p2 = __shfl_xor(v[2], 1, 64);
            float p3 = __shfl_xor(v[3], 1, 64);
            uint32_t u0 = codd ? pack2((bf16_t)p2, (bf16_t)v[2])
                               : pack2((bf16_t)v[0], (bf16_t)p0);
            uint32_t u1 = codd ? pack2((bf16_t)p3, (bf16_t)v[3])
                               : pack2((bf16_t)v[1], (bf16_t)p1);
            int dcol = d & ~1;
            int m = mbase + (codd ? 2 : 0);
            {
                int b_ = m >> 12, s = m & 4095;
                *(uint32_t*)&dst[((size_t)(b_ * NH + h) * SEQ + s) * HD + dcol] = u0;
                m++;
                b_ = m >> 12; s = m & 4095;
                *(uint32_t*)&dst[((size_t)(b_ * NH + h) * SEQ + s) * HD + dcol] = u1;
            }
        }
    }
}

// ---------------- GEMM2: bf16 Y @ fp32 Wo^T (cast fused), 128x64 tiles ----------------
// A (Yb bf16) via DMA dbuf; B (Wo fp32) via reg-prefetch + cvt + ds_write.
__global__ __launch_bounds__(256) void gemm_out(const bf16_t* __restrict__ A,
                                                const float* __restrict__ Wo,
                                                float* __restrict__ out) {
    __shared__ bf16_t As[2 * 128 * 32];   // 16 KB
    __shared__ bf16_t Bs[2 * 64 * 32];    // 8 KB
    const int t = threadIdx.x;
    const int lane = t & 63;
    const int wid = t >> 6;
    const int c = lane & 15, quad = lane >> 4;
    const int m0 = blockIdx.x * 128;
    const int n0 = blockIdx.y * 64;

    f32x4 acc[2][4];
#pragma unroll
    for (int i = 0; i < 2; i++)
#pragma unroll
        for (int j = 0; j < 4; j++) acc[i][j] = f32x4{0.f, 0.f, 0.f, 0.f};

    const int lrow = lane >> 2;
    const int lch = lane & 3;
    const bf16_t* Ag = A + (size_t)(m0 + wid * 32 + lrow) * 512 + lch * 8;
    const int aw0 = (wid * 32) * 32;
    const int aw1 = (wid * 32 + 16) * 32;

    // B staging: lane covers row wid*16 + (lane>>2), cols (lane&3)*8..+7
    const float* Bg32 = Wo + (size_t)(n0 + wid * 16 + (lane >> 2)) * 512 + (lane & 3) * 8;
    bf16_t* Bw = Bs + (wid * 16 + (lane >> 2)) * 32 + (lane & 3) * 8;

    // pre-loop
    gl_lds16(Ag, As + aw0);
    gl_lds16(Ag + 16 * 512, As + aw1);
    float4 br0 = *reinterpret_cast<const float4*>(Bg32);
    float4 br1 = *reinterpret_cast<const float4*>(Bg32 + 4);

    for (int it = 0; it < 16; it++) {
        // write B(it) regs -> LDS buf[it&1]
        bf16_t* bw = Bw + (it & 1) * 2048;
        *reinterpret_cast<bf16x4*>(bw) = cvt4(br0);
        *reinterpret_cast<bf16x4*>(bw + 4) = cvt4(br1);

        __syncthreads();   // drains A-DMA(it); B writes visible; prev readers done

        if (it + 1 < 16) {
            int k0 = (it + 1) * 32;
            int ao = ((it + 1) & 1) * 4096;
            gl_lds16(Ag + k0, As + ao + aw0);
            gl_lds16(Ag + 16 * 512 + k0, As + ao + aw1);
            br0 = *reinterpret_cast<const float4*>(Bg32 + k0);
            br1 = *reinterpret_cast<const float4*>(Bg32 + k0 + 4);
        }

        const bf16_t* Ab = As + (it & 1) * 4096;
        const bf16_t* Bb = Bs + (it & 1) * 2048;
        bf16x8 a[2], b[4];
#pragma unroll
        for (int i = 0; i < 2; i++) a[i] = ld8(&Ab[(wid * 32 + i * 16 + c) * 32 + quad * 8]);
#pragma unroll
        for (int j = 0; j < 4; j++) b[j] = ld8(&Bb[(j * 16 + c) * 32 + quad * 8]);
#pragma unroll
        for (int i = 0; i < 2; i++)
#pragma unroll
            for (int j = 0; j < 4; j++) acc[i][j] = mfma16(a[i], b[j], acc[i][j]);
    }

#pragma unroll
    for (int i = 0; i < 2; i++) {
        int mbase = m0 + wid * 32 + i * 16 + quad * 4;
#pragma unroll
        for (int j = 0; j < 4; j++) {
            int col = n0 + j * 16 + c;
#pragma unroll
            for (int r = 0; r < 4; r++)
                out[(size_t)(mbase + r) * DMODEL + col] = acc[i][j][r];
        }
    }
}

// ---------------- Flash attention (r16: r12 core + XCD-affinity swizzle) ----------------
// 1D grid of 512; bh = id & 15 so id mod 8 == bh mod 8 -> one head's KV per
// XCD L2 (FETCH 71.6 -> 14.3 MB measured r16). Core = r12: K via swizzled-
// source DMA dbuf, V reg-prefetch + transposed ds_write dbuf, 1 barrier/iter,
// exp2-domain softmax without max-subtraction. Reg-file-bound at 2
// waves/SIMD — do NOT reorder compute phases (r13) or raise launch_bounds w
// (r5/r7).
__global__ __launch_bounds__(256, 2) void flash_attn(const bf16_t* __restrict__ Q,
                                                     const bf16_t* __restrict__ K,
                                                     const bf16_t* __restrict__ V,
                                                     bf16_t* __restrict__ Y) {
    // per pair 32768 B: K buf0 8K | K buf1 8K | V^T buf0 8K | V^T buf1 8K
    __shared__ __align__(16) unsigned char smem[65536];

    const int t = threadIdx.x;
    const int lane = t & 63;
    const int c = lane & 15, quad = lane >> 4;
    const int wid = t >> 6;            // 0..3
    const int w = wid & 1;             // q-wave id == K-stage half id
    const int pr = wid >> 1;           // kv pair 0/1
    const int bh = blockIdx.x & 15;    // XCD-affinity: id%8 == bh%8
    const int qx = blockIdx.x >> 4;
    const int qw = qx * 128 + w * 64;

    size_t base = (size_t)bh * SEQ * HD;
    const bf16_t* Qp = Q + base;
    const bf16_t* Vp = V + base + (size_t)pr * 2048 * HD;

    unsigned char* pairBase = smem + pr * 32768;

    // K DMA swizzled source pointers: wave w stages tile rows [w*32, w*32+32)
    const bf16_t* Kpb = K + base + (size_t)pr * 2048 * HD;
    int srcOff = w * 4096 + ((lane >> 3) * 128) +
                 (((lane & 7) ^ ((lane >> 3) & 3)) * 16);
    const bf16_t* kE = (const bf16_t*)((const unsigned char*)Kpb + srcOff);
    const bf16_t* kO = (const bf16_t*)((const unsigned char*)Kpb + (srcOff ^ 64));

    bf16x8 qf[4][2];
#pragma unroll
    for (int qt = 0; qt < 4; qt++)
#pragma unroll
        for (int ks = 0; ks < 2; ks++)
            qf[qt][ks] = ld8(Qp + (size_t)(qw + qt * 16 + c) * HD + ks * 32 + quad * 8);

    f32x4 acc[4][4];
#pragma unroll
    for (int qt = 0; qt < 4; qt++)
#pragma unroll
        for (int dt = 0; dt < 4; dt++) acc[qt][dt] = f32x4{0.f, 0.f, 0.f, 0.f};
    float lsum[4] = {0.f, 0.f, 0.f, 0.f};

    // V staging (pair's 128 threads): rows kva,kva+1, d in [dc, dc+16)
    const int tp = t & 127;
    const int kva = 2 * (tp & 31);
    const int dc = 16 * (tp >> 5);

    // pre-loop: K tile 0 DMA into buf0; V tile 0 into regs
    {
        bf16_t* dst = (bf16_t*)(pairBase + w * 4096);
#pragma unroll
        for (int i = 0; i < 4; i++)
            gl_lds16(((i & 1) ? kO : kE) + i * 512, dst + i * 512);
        kE += 4096; kO += 4096;
    }
    bf16x8 vr0 = ld8(Vp + (size_t)kva * HD + dc);
    bf16x8 vr1 = ld8(Vp + (size_t)(kva + 1) * HD + dc);
    bf16x8 vr2 = ld8(Vp + (size_t)kva * HD + dc + 8);
    bf16x8 vr3 = ld8(Vp + (size_t)(kva + 1) * HD + dc + 8);

    for (int kt = 0; kt < 32; kt++) {
        uint32_t* vt = (uint32_t*)(pairBase + 16384 + (kt & 1) * 8192);

        // V transpose+swizzle stage for tile kt
#pragma unroll
        for (int j = 0; j < 8; j++) {
            int d0 = dc + j;
            int sv0 = (d0 & 7) ^ ((d0 >> 3) & 7);
            vt[d0 * 32 + (((kva >> 3) ^ sv0) & 7) * 4 + ((kva & 6) >> 1)] = pack2(vr0[j], vr1[j]);
            int d1 = dc + 8 + j;
            int sv1 = (d1 & 7) ^ ((d1 >> 3) & 7);
            vt[d1 * 32 + (((kva >> 3) ^ sv1) & 7) * 4 + ((kva & 6) >> 1)] = pack2(vr2[j], vr3[j]);
        }

        __syncthreads();   // drains K-DMA(kt), V writes visible, prev readers done

        // prefetch tile kt+1: K via DMA into other buf, V into regs
        if (kt + 1 < 32) {
            bf16_t* dst = (bf16_t*)(pairBase + ((kt + 1) & 1) * 8192 + w * 4096);
#pragma unroll
            for (int i = 0; i < 4; i++)
                gl_lds16(((i & 1) ? kO : kE) + i * 512, dst + i * 512);
            kE += 4096; kO += 4096;
            int kv0n = (kt + 1) * 64;
            vr0 = ld8(Vp + (size_t)(kv0n + kva) * HD + dc);
            vr1 = ld8(Vp + (size_t)(kv0n + kva + 1) * HD + dc);
            vr2 = ld8(Vp + (size_t)(kv0n + kva) * HD + dc + 8);
            vr3 = ld8(Vp + (size_t)(kv0n + kva + 1) * HD + dc + 8);
        }

        const uint4* kl = (const uint4*)(pairBase + (kt & 1) * 8192);

        // S^T = K*Q^T, kv-permuted rows
        f32x4 st[4][4];
#pragma unroll
        for (int n = 0; n < 4; n++) {
            int kvr = (n >> 1) * 32 + ((c >> 2) * 8) + ((n & 1) * 4) + (c & 3);
            int sk = (kvr & 3) | (((kvr >> 3) & 1) << 2);
            bf16x8 k0 = *reinterpret_cast<const bf16x8*>(&kl[kvr * 8 + (quad ^ sk)]);
            bf16x8 k1 = *reinterpret_cast<const bf16x8*>(&kl[kvr * 8 + ((4 + quad) ^ sk)]);
#pragma unroll
            for (int qt = 0; qt < 4; qt++) {
                f32x4 z = f32x4{0.f, 0.f, 0.f, 0.f};
                z = mfma16(k0, qf[qt][0], z);
                z = mfma16(k1, qf[qt][1], z);
                st[qt][n] = z;
            }
        }

        // softmax without max-subtraction (exp2 domain)
        bf16x8 pf[4][2];
#pragma unroll
        for (int qt = 0; qt < 4; qt++) {
            float e[4][4];
            float ls = 0.f;
#pragma unroll
            for (int n = 0; n < 4; n++)
#pragma unroll
                for (int r = 0; r < 4; r++) {
                    float v = __builtin_amdgcn_exp2f(st[qt][n][r]);
                    e[n][r] = v;
                    ls += v;
                }
            lsum[qt] += ls;
            bf16x8 f0, f1;
#pragma unroll
            for (int j = 0; j < 8; j++) {
                f0[j] = (bf16_t)e[(j >> 2)][j & 3];
                f1[j] = (bf16_t)e[2 + (j >> 2)][j & 3];
            }
            pf[qt][0] = f0;
            pf[qt][1] = f1;
        }

        // O^T += V^T * P^T
#pragma unroll
        for (int dt = 0; dt < 4; dt++) {
            int d = dt * 16 + c;
            int sv = (d & 7) ^ ((d >> 3) & 7);
            bf16x8 v0f = *reinterpret_cast<const bf16x8*>(&vt[d * 32 + ((quad ^ sv) & 7) * 4]);
            bf16x8 v1f = *reinterpret_cast<const bf16x8*>(&vt[d * 32 + (((4 + quad) ^ sv) & 7) * 4]);
#pragma unroll
            for (int qt = 0; qt < 4; qt++) {
                acc[qt][dt] = mfma16(v0f, pf[qt][0], acc[qt][dt]);
                acc[qt][dt] = mfma16(v1f, pf[qt][1], acc[qt][dt]);
            }
        }
    }

    float lred[4];
#pragma unroll
    for (int qt = 0; qt < 4; qt++) {
        float lt = lsum[qt];
        lt += __shfl_xor(lt, 16, 64);
        lt += __shfl_xor(lt, 32, 64);
        lred[qt] = lt;
    }

    // in-block pair-combine via LDS overlay
    __syncthreads();
    float* Ox = (float*)smem;
    float* Lx = (float*)(smem + 128 * 68 * 4);

    if (pr == 1) {
#pragma unroll
        for (int qt = 0; qt < 4; qt++) {
            int ql = w * 64 + qt * 16 + c;
#pragma unroll
            for (int dt = 0; dt < 4; dt++)
                *reinterpret_cast<f32x4*>(&Ox[ql * 68 + dt * 16 + quad * 4]) = acc[qt][dt];
            if (quad == 0) Lx[ql] = lred[qt];
        }
    }
    __syncthreads();
    if (pr == 0) {
        int b_ = bh >> 3, h = bh & 7;
#pragma unroll
        for (int qt = 0; qt < 4; qt++) {
            int ql = w * 64 + qt * 16 + c;
            float inv_l = 1.0f / (lred[qt] + Lx[ql]);
            int srow = qw + qt * 16 + c;
            bf16_t* yrow = Y + (size_t)(b_ * SEQ + srow) * DMODEL + h * HD;
#pragma unroll
            for (int dt = 0; dt < 4; dt++) {
                f32x4 o4 = acc[qt][dt] + *reinterpret_cast<const f32x4*>(&Ox[ql * 68 + dt * 16 + quad * 4]);
                bf16x4 o;
#pragma unroll
                for (int r = 0; r < 4; r++) o[r] = (bf16_t)(o4[r] * inv_l);
                *reinterpret_cast<bf16x4*>(yrow + dt * 16 + quad * 4) = o;
            }
        }
    }
}

extern "C" void kernel_launch(void* const* d_in, const int* in_sizes, int n_in,
                              void* d_out, int out_size, void* d_ws, size_t ws_size,
                              hipStream_t stream) {
    (void)in_sizes; (void)n_in; (void)out_size; (void)ws_size;
    const float* x  = (const float*)d_in[0];
    const float* Wq = (const float*)d_in[1];
    const float* Wk = (const float*)d_in[2];
    const float* Wv = (const float*)d_in[3];
    const float* Wo = (const float*)d_in[4];
    const int*   Vp = (const int*)d_in[6];
    float* out = (float*)d_out;

    bf16_t* ws  = (bf16_t*)d_ws;
    bf16_t* Qb  = ws;
    bf16_t* Kb  = Qb + 4194304;
    bf16_t* Vb  = Kb + 4194304;
    bf16_t* Yb  = Vb + 4194304;

    gemm_qkv<<<dim3(64, 12), 256, 0, stream>>>(x, Wq, Wk, Wv, Qb, Kb, Vb, Vp);

    flash_attn<<<512, 256, 0, stream>>>(Qb, Kb, Vb, Yb);

    gemm_out<<<dim3(64, 8), 256, 0, stream>>>(Yb, Wo, out);
}